// Round 5
// baseline (335.001 us; speedup 1.0000x reference)
//
#include <hip/hip_runtime.h>
#include <stdint.h>

// XLA emits multiply and add as separate uncontracted HLOs; HIP's default
// -ffp-contract=fast would fuse them into fma and break bit-exact RNG/score
// reproduction. Kill contraction globally.
#pragma clang fp contract(off)

// ---- Threefry-2x32, 20 rounds, exact JAX schedule ----
__host__ __device__ inline void tf2x32(uint32_t k0, uint32_t k1,
                                       uint32_t x0, uint32_t x1,
                                       uint32_t* o0, uint32_t* o1) {
  const uint32_t ks2 = k0 ^ k1 ^ 0x1BD11BDAu;
  x0 += k0; x1 += k1;
#define TF_R(r) { x0 += x1; x1 = (x1 << (r)) | (x1 >> (32 - (r))); x1 ^= x0; }
  TF_R(13) TF_R(15) TF_R(26) TF_R(6)
  x0 += k1;  x1 += ks2 + 1u;
  TF_R(17) TF_R(29) TF_R(16) TF_R(24)
  x0 += ks2; x1 += k0 + 2u;
  TF_R(13) TF_R(15) TF_R(26) TF_R(6)
  x0 += k0;  x1 += k1 + 3u;
  TF_R(17) TF_R(29) TF_R(16) TF_R(24)
  x0 += k1;  x1 += ks2 + 4u;
  TF_R(13) TF_R(15) TF_R(26) TF_R(6)
  x0 += ks2; x1 += k0 + 5u;
#undef TF_R
  *o0 = x0; *o1 = x1;
}

// ---- XLA ErfInv32 (Giles coefficients, exact op order) ----
__device__ inline float erfinv_xla(float x) {
#pragma clang fp contract(off)
  float w = -log1pf(-(x * x));
  float p;
  if (w < 5.0f) {
    w = w - 2.5f;
    p = 2.81022636e-08f;
    p = 3.43273939e-07f  + p * w;
    p = -3.5233877e-06f  + p * w;
    p = -4.39150654e-06f + p * w;
    p = 0.00021858087f   + p * w;
    p = -0.00125372503f  + p * w;
    p = -0.00417768164f  + p * w;
    p = 0.246640727f     + p * w;
    p = 1.50140941f      + p * w;
  } else {
    w = sqrtf(w) - 3.0f;
    p = -0.000200214257f;
    p = 0.000100950558f  + p * w;
    p = 0.00134934322f   + p * w;
    p = -0.00367342844f  + p * w;
    p = 0.00573950773f   + p * w;
    p = -0.0076224613f   + p * w;
    p = 0.00943887047f   + p * w;
    p = 1.00167406f      + p * w;
    p = 2.83297682f      + p * w;
  }
  return p * x;
}

// jax.random.normal element `idx` under key (k0,k1), partitionable stream.
__device__ inline float jax_normal(uint32_t k0, uint32_t k1, uint32_t idx) {
#pragma clang fp contract(off)
  uint32_t o0, o1;
  tf2x32(k0, k1, 0u, idx, &o0, &o1);
  uint32_t bits = o0 ^ o1;
  float f = __uint_as_float((bits >> 9) | 0x3f800000u) - 1.0f;
  float u = f * 2.0f + (-0x1.fffffep-1f);
  u = fmaxf(-0x1.fffffep-1f, u);
  return 0x1.6a09e6p+0f * erfinv_xla(u);  // float(sqrt(2)) * erfinv(u)
}

// Bilinear corr score; association matches XLA: ((t00+t01)+t10)+t11.
__device__ inline float score_at(const float* __restrict__ base, int stride,
                                 float x, float y) {
#pragma clang fp contract(off)
  float x0 = floorf(x), y0 = floorf(y);
  float wx = x - x0, wy = y - y0;
  int xi = (int)x0; xi = xi < 0 ? 0 : (xi > 63 ? 63 : xi);
  int yi = (int)y0; yi = yi < 0 ? 0 : (yi > 63 ? 63 : yi);
  int x1 = xi + 1 > 63 ? 63 : xi + 1;
  int y1 = yi + 1 > 63 ? 63 : yi + 1;
  float v00 = base[(yi * 64 + xi) * stride];
  float v01 = base[(yi * 64 + x1) * stride];
  float v10 = base[(y1 * 64 + xi) * stride];
  float v11 = base[(y1 * 64 + x1) * stride];
  float omx = 1.0f - wx, omy = 1.0f - wy;
  return (((v00 * omx) * omy + (v01 * wx) * omy) + (v10 * omx) * wy) + (v11 * wx) * wy;
}

// Fused propagate + random-search step. One pixel per thread, 512 blocks x
// 64 threads -> all 256 CUs active. Kernel-launch boundary is the global
// barrier between steps (R3: sw fabric barrier = ~65 us/phase; launch
// boundary is far cheaper). Buffer entry = (x, y, score, unused): carried
// score is bit-identical to the reference's per-step recompute.
__global__ __launch_bounds__(64) void step_kernel(
    const float* __restrict__ mf, const float* __restrict__ mb,
    const float4* __restrict__ in_c, float4* __restrict__ out_c,
    const float* __restrict__ corr, int dx, int dy,
    uint32_t k0f, uint32_t k1f, uint32_t k0b, uint32_t k1b,
    int from_matching) {
#pragma clang fp contract(off)
  int g = (int)(blockIdx.x * 64 + threadIdx.x);   // 0..32767
  int dir = g >> 14, b = (g >> 12) & 3, p = g & 4095;
  int i = p >> 6, j = p & 63;

  const float* base; int stride;
  if (dir == 0) { base = corr + (size_t)(b * 4096 + p) * 4096; stride = 1; }
  else          { base = corr + (size_t)b * 16777216 + p;      stride = 4096; }

  int jh = (j - dx) & 63;            // roll along W
  int iv = (i - dy) & 63;            // roll along H

  float2 bst; float bs;
  float2 ch, cv;
  if (from_matching) {
    const float* m = dir ? mb : mf;
    float2 c = make_float2(m[((b * 2 + 0) * 64 + i) * 64 + j],
                           m[((b * 2 + 1) * 64 + i) * 64 + j]);
    ch = make_float2(m[((b * 2 + 0) * 64 + i ) * 64 + jh], m[((b * 2 + 1) * 64 + i ) * 64 + jh]);
    cv = make_float2(m[((b * 2 + 0) * 64 + iv) * 64 + j ], m[((b * 2 + 1) * 64 + iv) * 64 + j ]);
    bst = c;
    bs = score_at(base, stride, c.x, c.y);
  } else {
    const float4* ic = in_c + dir * 16384 + b * 4096;
    float4 own = ic[p];
    float4 nh  = ic[(i << 6) | jh];
    float4 nv  = ic[(iv << 6) | j];
    bst = make_float2(own.x, own.y);
    bs  = own.z;                      // == score_at(own.xy), bit-exact
    ch = make_float2(nh.x, nh.y);
    cv = make_float2(nv.x, nv.y);
  }
  ch.x = fminf(fmaxf(ch.x + (float)dx, 0.0f), 63.0f);  // + [dx,0], clamp
  cv.y = fminf(fmaxf(cv.y + (float)dy, 0.0f), 63.0f);  // + [0,dy], clamp

  float sh = score_at(base, stride, ch.x, ch.y);
  float sv = score_at(base, stride, cv.x, cv.y);
  if (sh > bs) bst = ch;                // upd = s > best_s
  bs = fmaxf(sh, bs);
  if (sv > bs) bst = cv;
  bs = fmaxf(sv, bs);

  // random search (all steps that use this kernel have one)
  uint32_t kk0 = dir ? k0b : k0f, kk1 = dir ? k1b : k1f;
  uint32_t pg = (uint32_t)(b * 4096 + p);        // flat (b,i,j) over (4,64,64)
  float n0 = jax_normal(kk0, kk1, 2u * pg);
  float n1 = jax_normal(kk0, kk1, 2u * pg + 1u);
  float nx = fminf(fmaxf(bst.x + 3.0f * n0, 0.0f), 63.0f);
  float ny = fminf(fmaxf(bst.y + 3.0f * n1, 0.0f), 63.0f);
  float sn = score_at(base, stride, nx, ny);
  if (sn - bs > 0.0f) { bst = make_float2(nx, ny); bs = sn; }  // new_s - 1.0*old_s > 0

  out_c[dir * 16384 + b * 4096 + p] = make_float4(bst.x, bst.y, bs, 0.0f);
}

// Step 4 (propagate(+1,-1), no rs) is a pure per-pixel function of the step-3
// buffer, so this kernel recomputes it locally for the own dir-0 pixel AND the
// 4 dir-1 bilinear-corner pixels -- no barrier needed, one fewer launch.
// Recompute is bit-exact (same ops, same order as the step kernel would do).
__global__ __launch_bounds__(64) void step4_combine_kernel(
    const float* __restrict__ mf, const float4* __restrict__ in_c,
    const float* __restrict__ corr, float* __restrict__ out) {
#pragma clang fp contract(off)
  int pg = (int)(blockIdx.x * 64 + threadIdx.x);   // 0..16383 (dir-0 pixels)
  int b = pg >> 12, p = pg & 4095;
  int i = p >> 6, j = p & 63;

  // ---- step 4 for own dir-0 pixel (contiguous corr rows) ----
  float2 rf;
  {
    const float* base = corr + (size_t)(b * 4096 + p) * 4096;  // stride 1
    const float4* ic = in_c + b * 4096;                         // dir 0
    float4 own = ic[p];
    int jh = (j - 1) & 63, iv = (i + 1) & 63;   // dx=+1, dy=-1
    float4 nh = ic[(i << 6) | jh];
    float4 nv = ic[(iv << 6) | j];
    float2 ch = make_float2(fminf(fmaxf(nh.x + 1.0f, 0.0f), 63.0f), nh.y);
    float2 cv = make_float2(nv.x, fminf(fmaxf(nv.y - 1.0f, 0.0f), 63.0f));
    float sh = score_at(base, 1, ch.x, ch.y);
    float sv = score_at(base, 1, cv.x, cv.y);
    float2 bst = make_float2(own.x, own.y); float bs = own.z;
    if (sh > bs) bst = ch;
    bs = fmaxf(sh, bs);
    if (sv > bs) bst = cv;
    rf = bst;
  }

  // ---- bilinear corners of rf ----
  float x0 = floorf(rf.x), y0 = floorf(rf.y);
  float wx = rf.x - x0, wy = rf.y - y0;
  int xi = (int)x0; xi = xi < 0 ? 0 : (xi > 63 ? 63 : xi);
  int yi = (int)y0; yi = yi < 0 ? 0 : (yi > 63 ? 63 : yi);
  int x1 = xi + 1 > 63 ? 63 : xi + 1;
  int y1 = yi + 1 > 63 ? 63 : yi + 1;

  // ---- step 4 dir-1 recompute at a corner pixel (ci,cj) ----
  const float4* ic1 = in_c + 16384 + b * 4096;                 // dir 1
  const float* cb = corr + (size_t)b * 16777216;
  auto step4_b = [&](int ci, int cj) -> float2 {
#pragma clang fp contract(off)
    int q = (ci << 6) | cj;
    const float* base = cb + q;                                 // stride 4096
    float4 own = ic1[q];
    int jh = (cj - 1) & 63, iv = (ci + 1) & 63;
    float4 nh = ic1[(ci << 6) | jh];
    float4 nv = ic1[(iv << 6) | cj];
    float2 ch = make_float2(fminf(fmaxf(nh.x + 1.0f, 0.0f), 63.0f), nh.y);
    float2 cv = make_float2(nv.x, fminf(fmaxf(nv.y - 1.0f, 0.0f), 63.0f));
    float sh = score_at(base, 4096, ch.x, ch.y);
    float sv = score_at(base, 4096, cv.x, cv.y);
    float2 bst = make_float2(own.x, own.y); float bs = own.z;
    if (sh > bs) bst = ch;
    bs = fmaxf(sh, bs);
    if (sv > bs) bst = cv;
    return bst;
  };
  float2 v00 = step4_b(yi, xi);
  float2 v01 = step4_b(yi, x1);
  float2 v10 = step4_b(y1, xi);
  float2 v11 = step4_b(y1, x1);

  float omx = 1.0f - wx, omy = 1.0f - wy;
  float c0 = (((v00.x * omx) * omy + (v01.x * wx) * omy) + (v10.x * omx) * wy) + (v11.x * wx) * wy;
  float c1 = (((v00.y * omx) * omy + (v01.y * wx) * omy) + (v10.y * omx) * wy) + (v11.y * wx) * wy;
  float d = fmaxf(fabsf(rf.x - c0), fabsf(rf.y - c1));
  bool invalid = d > 0.01f;
  out[((b * 2 + 0) * 64 + i) * 64 + j] = invalid ? mf[((b * 2 + 0) * 64 + i) * 64 + j] : rf.x;
  out[((b * 2 + 1) * 64 + i) * 64 + j] = invalid ? mf[((b * 2 + 1) * 64 + i) * 64 + j] : rf.y;
}

extern "C" void kernel_launch(void* const* d_in, const int* in_sizes, int n_in,
                              void* d_out, int out_size, void* d_ws, size_t ws_size,
                              hipStream_t stream) {
  const float* mf   = (const float*)d_in[0];
  const float* mb   = (const float*)d_in[1];
  const float* corr = (const float*)d_in[2];
  float* out  = (float*)d_out;
  float4* bufA = (float4*)d_ws;             // [2][4][4096] float4 = 512 KB
  float4* bufB = bufA + 32768;              // second 512 KB

  // Host-side key derivation from seed 42 -> root key (0, 42).
  // split(root,2)[d] = enc_root(0, d); split(k,3)[s] = enc_k(0, s).
  uint32_t kf0, kf1, kb0, kb1, K[12];
  tf2x32(0u, 42u, 0u, 0u, &kf0, &kf1);
  tf2x32(0u, 42u, 0u, 1u, &kb0, &kb1);
  for (uint32_t s = 0; s < 3; ++s) {
    tf2x32(kf0, kf1, 0u, s, &K[0 + s * 2], &K[0 + s * 2 + 1]);
    tf2x32(kb0, kb1, 0u, s, &K[6 + s * 2], &K[6 + s * 2 + 1]);
  }

  dim3 grid(512), block(64);
  // step 1: propagate(+1,+1) from matching, + random_search(k1)
  step_kernel<<<grid, block, 0, stream>>>(mf, mb, nullptr, bufA, corr,  1,  1,
                                          K[0], K[1], K[6], K[7], 1);
  // step 2: propagate(-1,-1), + random_search(k2)
  step_kernel<<<grid, block, 0, stream>>>(mf, mb, bufA, bufB, corr, -1, -1,
                                          K[2], K[3], K[8], K[9], 0);
  // step 3: propagate(-1,+1), + random_search(k3)
  step_kernel<<<grid, block, 0, stream>>>(mf, mb, bufB, bufA, corr, -1,  1,
                                          K[4], K[5], K[10], K[11], 0);
  // step 4 (propagate(+1,-1), no rs) fused with combine: pure recompute, no barrier
  step4_combine_kernel<<<dim3(256), dim3(64), 0, stream>>>(mf, bufA, corr, out);
  (void)in_sizes; (void)n_in; (void)out_size; (void)ws_size;
}